// Round 11
// baseline (191.869 us; speedup 1.0000x reference)
//
#include <hip/hip_runtime.h>

#define BB 2
#define NN 2048
#define EE 768
#define HH 12
#define DD 64
#define MM (BB*NN)      // 4096
#define E3 (3*EE)       // 2304
// 1/sqrt(768) * log2(e): scores in log2 domain -> P = exp2(s)
#define QSCALE 0.05205877280961602f

typedef __bf16 bf16x8 __attribute__((ext_vector_type(8)));
typedef float  f32x4  __attribute__((ext_vector_type(4)));
typedef unsigned short u16x8 __attribute__((ext_vector_type(8)));
typedef short s16x4 __attribute__((ext_vector_type(4)));
typedef unsigned int u32x2 __attribute__((ext_vector_type(2)));

#define MFMA(a,b,c)   __builtin_amdgcn_mfma_f32_16x16x32_bf16(a,b,c,0,0,0)
#define MFMA16(a,b,c) __builtin_amdgcn_mfma_f32_16x16x16bf16_1k(a,b,c,0,0,0)

__device__ __forceinline__ unsigned short f2bf(float f) {
    unsigned int u = __float_as_uint(f);
    u += 0x7FFFu + ((u >> 16) & 1u);     // round-to-nearest-even
    return (unsigned short)(u >> 16);
}

typedef __attribute__((address_space(3))) unsigned int as3u32;
typedef __attribute__((address_space(1))) unsigned int as1u32;
__device__ __forceinline__ void gll16(const void* g, void* l) {
    // lane i deposits its 16B at lds_base + i*16 (wave-uniform dest base)
    __builtin_amdgcn_global_load_lds((const as1u32*)(uintptr_t)g,
                                     (as3u32*)(unsigned int)(uintptr_t)l, 16, 0, 0);
}

// ---------------------------------------------------------------------------
// fused f32 -> bf16 cast of x, w_qkv, w_o (contiguous dsts in ws)
// ---------------------------------------------------------------------------
#define XB4 786432   // (MM*EE)/4
#define WQ4 442368   // (E3*EE)/4
#define WO4 147456   // (EE*EE)/4
__global__ __launch_bounds__(256)
void cast3(const float* __restrict__ x, const float* __restrict__ wq,
           const float* __restrict__ wo, unsigned short* __restrict__ dst) {
    int i = blockIdx.x * 256 + threadIdx.x;
    const float* src;
    int off;
    if (i < XB4)            { src = x;  off = i; }
    else if (i < XB4+WQ4)   { src = wq; off = i - XB4; }
    else                    { src = wo; off = i - XB4 - WQ4; }
    float4 v = ((const float4*)src)[off];
    ushort4 o;
    o.x = f2bf(v.x); o.y = f2bf(v.y); o.z = f2bf(v.z); o.w = f2bf(v.w);
    ((ushort4*)dst)[i] = o;
}

// ---------------------------------------------------------------------------
// QKV GEMM (r7 known-good): 128x128 tile, BK=32, 4 waves, wave 64x64.
// Scatter: q (scaled) [B][H][N][D], k [B][H][N][D], v transposed [B][H][D][N].
// ---------------------------------------------------------------------------
__global__ __launch_bounds__(256)
void gemm_qkv(const unsigned short* __restrict__ A, const unsigned short* __restrict__ W,
              const float* __restrict__ bias,
              unsigned short* __restrict__ o0, unsigned short* __restrict__ o1,
              unsigned short* __restrict__ o2)
{
    __shared__ unsigned short As[128 * 32];
    __shared__ unsigned short Bs[128 * 32];

    const int tid = threadIdx.x;
    const int l = tid & 63;
    const int w = tid >> 6;
    const int m0 = blockIdx.x * 128;
    const int c0 = blockIdx.y * 128;
    const int wm = (w >> 1) * 64;
    const int wn = (w & 1) * 64;

    const int s0 = w * 2;
    const unsigned short* a_src0 = A + (size_t)(m0 + s0*16      + (l>>2)) * EE + (l&3)*8;
    const unsigned short* a_src1 = A + (size_t)(m0 + (s0+1)*16  + (l>>2)) * EE + (l&3)*8;
    const unsigned short* b_src0 = W + (size_t)(c0 + s0*16      + (l>>2)) * EE + (l&3)*8;
    const unsigned short* b_src1 = W + (size_t)(c0 + (s0+1)*16  + (l>>2)) * EE + (l&3)*8;
    unsigned short* a_dst0 = &As[s0*512];
    unsigned short* a_dst1 = &As[(s0+1)*512];
    unsigned short* b_dst0 = &Bs[s0*512];
    unsigned short* b_dst1 = &Bs[(s0+1)*512];

    const f32x4 zero4 = {0.f, 0.f, 0.f, 0.f};
    f32x4 acc[4][4];
    #pragma unroll
    for (int i = 0; i < 4; ++i)
        #pragma unroll
        for (int j = 0; j < 4; ++j) acc[i][j] = zero4;

    for (int k0 = 0; k0 < EE; k0 += 32) {
        __syncthreads();
        gll16(a_src0 + k0, a_dst0);
        gll16(a_src1 + k0, a_dst1);
        gll16(b_src0 + k0, b_dst0);
        gll16(b_src1 + k0, b_dst1);
        __syncthreads();

        bf16x8 af[4], bf[4];
        #pragma unroll
        for (int i = 0; i < 4; ++i)
            af[i] = *(const bf16x8*)&As[(wm + 16*i + (l&15))*32 + (l>>4)*8];
        #pragma unroll
        for (int j = 0; j < 4; ++j)
            bf[j] = *(const bf16x8*)&Bs[(wn + 16*j + (l&15))*32 + (l>>4)*8];
        #pragma unroll
        for (int i = 0; i < 4; ++i)
            #pragma unroll
            for (int j = 0; j < 4; ++j)
                acc[i][j] = MFMA(af[i], bf[j], acc[i][j]);
    }

    const int sec = (c0 + wn) >> 6;        // = hh*3 + tt
    const int hh = sec / 3;
    const int tt = sec - hh*3;
    #pragma unroll
    for (int j = 0; j < 4; ++j) {
        const int col = c0 + wn + 16*j + (l&15);
        const int dcol = 16*j + (l&15);
        const float bj = bias[col];
        #pragma unroll
        for (int i = 0; i < 4; ++i) {
            const int row0 = m0 + wm + 16*i + (l>>4)*4;
            const int b = row0 >> 11;
            const int n = row0 & (NN - 1);
            if (tt == 2) {
                ushort4 pk;
                pk.x = f2bf(acc[i][j][0] + bj);
                pk.y = f2bf(acc[i][j][1] + bj);
                pk.z = f2bf(acc[i][j][2] + bj);
                pk.w = f2bf(acc[i][j][3] + bj);
                *(ushort4*)&o2[(((size_t)b*HH + hh)*DD + dcol)*NN + n] = pk;
            } else {
                unsigned short* dst = (tt == 0) ? o0 : o1;
                #pragma unroll
                for (int r = 0; r < 4; ++r) {
                    float val = acc[i][j][r] + bj;
                    if (tt == 0) val *= QSCALE;
                    dst[(((size_t)b*HH + hh)*NN + n + r)*DD + dcol] = f2bf(val);
                }
            }
        }
    }
}

// ---------------------------------------------------------------------------
// Output GEMM (r7): 64x128 tile, BK=32, 4 waves, wave tile 32x64 (2x4 frags).
// ---------------------------------------------------------------------------
__global__ __launch_bounds__(256)
void gemm_out(const unsigned short* __restrict__ A, const unsigned short* __restrict__ W,
              const float* __restrict__ bias, float* __restrict__ of)
{
    __shared__ unsigned short As[64 * 32];    // 4 KB
    __shared__ unsigned short Bs[128 * 32];   // 8 KB

    const int tid = threadIdx.x;
    const int l = tid & 63;
    const int w = tid >> 6;
    const int m0 = blockIdx.x * 64;
    const int c0 = blockIdx.y * 128;
    const int wm = (w >> 1) * 32;
    const int wn = (w & 1) * 64;

    const unsigned short* s_src[3];
    unsigned short* s_dst[3];
    #pragma unroll
    for (int s = 0; s < 3; ++s) {
        const int ch = 3*w + s;
        if (ch < 4) {
            s_src[s] = A + (size_t)(m0 + ch*16 + (l>>2)) * EE + (l&3)*8;
            s_dst[s] = &As[ch*512];
        } else {
            s_src[s] = W + (size_t)(c0 + (ch-4)*16 + (l>>2)) * EE + (l&3)*8;
            s_dst[s] = &Bs[(ch-4)*512];
        }
    }

    const f32x4 zero4 = {0.f, 0.f, 0.f, 0.f};
    f32x4 acc[2][4];
    #pragma unroll
    for (int i = 0; i < 2; ++i)
        #pragma unroll
        for (int j = 0; j < 4; ++j) acc[i][j] = zero4;

    for (int k0 = 0; k0 < EE; k0 += 32) {
        __syncthreads();
        #pragma unroll
        for (int s = 0; s < 3; ++s) gll16(s_src[s] + k0, s_dst[s]);
        __syncthreads();

        bf16x8 af[2], bf[4];
        #pragma unroll
        for (int i = 0; i < 2; ++i)
            af[i] = *(const bf16x8*)&As[(wm + 16*i + (l&15))*32 + (l>>4)*8];
        #pragma unroll
        for (int j = 0; j < 4; ++j)
            bf[j] = *(const bf16x8*)&Bs[(wn + 16*j + (l&15))*32 + (l>>4)*8];
        #pragma unroll
        for (int i = 0; i < 2; ++i)
            #pragma unroll
            for (int j = 0; j < 4; ++j)
                acc[i][j] = MFMA(af[i], bf[j], acc[i][j]);
    }

    #pragma unroll
    for (int j = 0; j < 4; ++j) {
        const int col = c0 + wn + 16*j + (l&15);
        const float bj = bias[col];
        #pragma unroll
        for (int i = 0; i < 2; ++i) {
            #pragma unroll
            for (int r = 0; r < 4; ++r) {
                const int row = m0 + wm + 16*i + (l>>4)*4 + r;
                of[(size_t)row * EE + col] = acc[i][j][r] + bj;
            }
        }
    }
}

// ---------------------------------------------------------------------------
// MFMA flash attention, KEY-SPLIT over LDS-staged tiles.
// Block = 64 q of one (b,h); 4 waves; wave w owns keys [16w,16w+16) of each
// staged 64-key tile, ALL 64 q (Q B-frags register-resident).
// -> each staged K/V element is LDS-read by exactly ONE wave (minimal traffic:
//    10 LDS ops/wave/tile vs 26 in r7), and P chains S^T -> PV entirely in
//    registers (C-layout == B-layout of mfma_f32_16x16x16bf16_1k; r9-verified).
// Partial O / lsum per wave over its key subset; r9-verified LDS tree epilogue.
// Ks [64][64] r7-swizzled (16B chunk ^ row&7); Vt [64][72] padded (b64 reads).
// Grid 768: bh = id%24 (XCD-grouped), bq = id/24.
// ---------------------------------------------------------------------------
__global__ __launch_bounds__(256)
void attn_mfma(const unsigned short* __restrict__ Qg, const unsigned short* __restrict__ K,
               const unsigned short* __restrict__ Vt_g, unsigned short* __restrict__ ctx)
{
    // unions: [Qs 8KB | Ks 8KB] + Vt 9.25KB during loop; Red+Ls (35840 B) after
    __shared__ unsigned char smem[35840];
    unsigned short* Qs = (unsigned short*)smem;            // [64][64]
    unsigned short* Ks = (unsigned short*)smem;            // [64][64] swizzled
    unsigned short* Vt = (unsigned short*)(smem + 16384);  // [64][72]
    float* Red = (float*)smem;                             // 2 x [64][68]
    float* Ls  = (float*)(smem + 34816);                   // [4][64]

    const int tid = threadIdx.x;
    const int l = tid & 63;
    const int w = tid >> 6;
    const int quad = l >> 4;
    const int lc = l & 15;
    const int x7 = lc & 7;

    const int id = blockIdx.x;
    const int bh = id % 24;              // b*HH + h
    const int bq = id / 24;              // q-tile
    const int b  = bh / 12;
    const int h  = bh - b*12;
    const size_t hb = (size_t)bh * NN * DD;

    const f32x4 zero4 = {0.f, 0.f, 0.f, 0.f};

    // stage Q tile (64 q x 64 d) into LDS, coalesced; then frags to registers
    {
        const int row = tid >> 2;
        const int col = (tid & 3) * 16;
        const unsigned short* src = Qg + hb + (size_t)(bq*64 + row)*DD + col;
        u16x8 qa = *(const u16x8*)src;
        u16x8 qb2 = *(const u16x8*)(src + 8);
        *(u16x8*)&Qs[row*64 + col]     = qa;
        *(u16x8*)&Qs[row*64 + col + 8] = qb2;
    }
    __syncthreads();
    bf16x8 qf[4][2];                     // B[n=q=g*16+lc][k=d=ks*32+quad*8+j]
    #pragma unroll
    for (int g = 0; g < 4; ++g)
        #pragma unroll
        for (int ks = 0; ks < 2; ++ks)
            qf[g][ks] = *(const bf16x8*)&Qs[(g*16 + lc)*64 + ks*32 + quad*8];

    f32x4 O[4][4];                       // [d-block][q-group], partial over keys
    #pragma unroll
    for (int db = 0; db < 4; ++db)
        #pragma unroll
        for (int g = 0; g < 4; ++g) O[db][g] = zero4;
    float lsum[4] = {0.f, 0.f, 0.f, 0.f};

    // staging: 256 threads, row = tid>>2 (64 rows), sc = tid&3 (2 x 16B)
    const int srow = tid >> 2;
    const int sc = tid & 3;
    const unsigned short* kbase = K + hb + (size_t)srow*DD + sc*16;
    const unsigned short* vbase = Vt_g + hb + (size_t)srow*NN + sc*16;
    const int c0s = ((2*sc)     ^ (srow & 7)) * 8;
    const int c1s = ((2*sc + 1) ^ (srow & 7)) * 8;

    // K A-frag addresses: row = 16w + lc (swizzle phase lc&7, w-independent)
    const int krow = (16*w + lc) * 64;
    const int chq0 = ((    quad) ^ x7) * 8;
    const int chq1 = ((4 + quad) ^ x7) * 8;
    // V A-frag: Vt[(16db+lc)][16w + quad*4], b64
    const int voff = 16*w + quad*4;

    for (int kt = 0; kt < NN/64; ++kt) {
        const unsigned short* ksrc = kbase + (size_t)kt*64*DD;
        const unsigned short* vsrc = vbase + kt*64;
        u16x8 k0 = *(const u16x8*)ksrc;
        u16x8 k1 = *(const u16x8*)(ksrc + 8);
        u16x8 v0 = *(const u16x8*)vsrc;
        u16x8 v1 = *(const u16x8*)(vsrc + 8);
        __syncthreads();                 // prior-iter readers (and Qs reads) done
        *(u16x8*)&Ks[srow*64 + c0s] = k0;
        *(u16x8*)&Ks[srow*64 + c1s] = k1;
        *(u16x8*)&Vt[srow*72 + sc*16]     = v0;
        *(u16x8*)&Vt[srow*72 + sc*16 + 8] = v1;
        __syncthreads();                 // writers done

        // S^T = K Q^T for wave's 16 keys x all 64 q
        bf16x8 kf0 = *(const bf16x8*)&Ks[krow + chq0];
        bf16x8 kf1 = *(const bf16x8*)&Ks[krow + chq1];
        f32x4 st[4];
        #pragma unroll
        for (int g = 0; g < 4; ++g) {
            f32x4 t0 = MFMA(kf0, qf[g][0], zero4);
            st[g] = MFMA(kf1, qf[g][1], t0);
        }

        // P = exp2(S^T) packed in-register (C-layout == MFMA16 B-layout)
        s16x4 pf[4];
        #pragma unroll
        for (int g = 0; g < 4; ++g) {
            float e0 = __builtin_amdgcn_exp2f(st[g][0]);
            float e1 = __builtin_amdgcn_exp2f(st[g][1]);
            float e2 = __builtin_amdgcn_exp2f(st[g][2]);
            float e3 = __builtin_amdgcn_exp2f(st[g][3]);
            lsum[g] += (e0 + e1) + (e2 + e3);
            unsigned int p01 = __builtin_amdgcn_perm(__float_as_uint(e1) + 0x8000u,
                                                     __float_as_uint(e0) + 0x8000u, 0x07060302u);
            unsigned int p23 = __builtin_amdgcn_perm(__float_as_uint(e3) + 0x8000u,
                                                     __float_as_uint(e2) + 0x8000u, 0x07060302u);
            u32x2 pp = {p01, p23};
            pf[g] = __builtin_bit_cast(s16x4, pp);
        }

        // O^T += V^T P^T (k = wave's 16 keys), V A-frags b64 from padded Vt
        #pragma unroll
        for (int db = 0; db < 4; ++db) {
            s16x4 vfr = *(const s16x4*)&Vt[(16*db + lc)*72 + voff];
            #pragma unroll
            for (int g = 0; g < 4; ++g)
                O[db][g] = MFMA16(vfr, pf[g], O[db][g]);
        }
    }

    // ---- epilogue: combine 4 waves' partial O / lsum (r9-verified) ----
    #pragma unroll
    for (int g = 0; g < 4; ++g) {
        lsum[g] += __shfl_xor(lsum[g], 16);
        lsum[g] += __shfl_xor(lsum[g], 32);
    }
    __syncthreads();                     // all compute done; safe to reuse LDS
    if (quad == 0) {
        #pragma unroll
        for (int g = 0; g < 4; ++g) Ls[w*64 + g*16 + lc] = lsum[g];
    }
    if (w & 1) {
        float* R = Red + (w >> 1) * 4352;
        #pragma unroll
        for (int db = 0; db < 4; ++db)
            #pragma unroll
            for (int g = 0; g < 4; ++g)
                *(f32x4*)&R[(g*16 + lc)*68 + db*16 + quad*4] = O[db][g];
    }
    __syncthreads();
    if (!(w & 1)) {
        float* R = Red + (w >> 1) * 4352;
        #pragma unroll
        for (int db = 0; db < 4; ++db)
            #pragma unroll
            for (int g = 0; g < 4; ++g)
                O[db][g] += *(const f32x4*)&R[(g*16 + lc)*68 + db*16 + quad*4];
    }
    __syncthreads();
    if (w == 2) {
        #pragma unroll
        for (int db = 0; db < 4; ++db)
            #pragma unroll
            for (int g = 0; g < 4; ++g)
                *(f32x4*)&Red[(g*16 + lc)*68 + db*16 + quad*4] = O[db][g];
    }
    __syncthreads();
    if (w == 0) {
        float inv[4];
        #pragma unroll
        for (int g = 0; g < 4; ++g) {
            const int q = g*16 + lc;
            inv[g] = 1.f / (Ls[q] + Ls[64 + q] + Ls[128 + q] + Ls[192 + q]);
        }
        #pragma unroll
        for (int db = 0; db < 4; ++db) {
            #pragma unroll
            for (int g = 0; g < 4; ++g) {
                f32x4 o = O[db][g] + *(const f32x4*)&Red[(g*16 + lc)*68 + db*16 + quad*4];
                ushort4 pk;
                pk.x = f2bf(o[0] * inv[g]);
                pk.y = f2bf(o[1] * inv[g]);
                pk.z = f2bf(o[2] * inv[g]);
                pk.w = f2bf(o[3] * inv[g]);
                const int n = bq*64 + g*16 + lc;
                *(ushort4*)&ctx[((size_t)(b*NN + n))*EE + h*DD + db*16 + quad*4] = pk;
            }
        }
    }
}

// ---------------------------------------------------------------------------
extern "C" void kernel_launch(void* const* d_in, const int* in_sizes, int n_in,
                              void* d_out, int out_size, void* d_ws, size_t ws_size,
                              hipStream_t stream)
{
    const float* x     = (const float*)d_in[0];
    const float* w_qkv = (const float*)d_in[1];
    const float* b_qkv = (const float*)d_in[2];
    const float* w_o   = (const float*)d_in[3];
    const float* b_o   = (const float*)d_in[4];
    float* out = (float*)d_out;

    unsigned short* wsu = (unsigned short*)d_ws;
    const size_t XB = (size_t)MM * EE;
    const size_t WQ = (size_t)E3 * EE;
    const size_t WO = (size_t)EE * EE;
    const size_t HS = (size_t)BB * HH * NN * DD;
    unsigned short* xb   = wsu;
    unsigned short* wqb  = xb  + XB;
    unsigned short* wob  = wqb + WQ;
    unsigned short* qb   = wob + WO;      // [B][H][N][D] (scaled)
    unsigned short* kb   = qb  + HS;      // [B][H][N][D]
    unsigned short* vtb  = kb  + HS;      // [B][H][D][N]
    unsigned short* ctxb = vtb + HS;

    cast3<<<(XB4 + WQ4 + WO4)/256, 256, 0, stream>>>(x, w_qkv, w_o, xb);

    dim3 g1(MM/128, E3/128);   // 32 x 18 = 576 blocks
    gemm_qkv<<<g1, 256, 0, stream>>>(xb, wqb, b_qkv, qb, kb, vtb);

    attn_mfma<<<768, 256, 0, stream>>>(qb, kb, vtb, ctxb);

    dim3 g3(MM/64, EE/128);    // 64 x 6 = 384 blocks
    gemm_out<<<g3, 256, 0, stream>>>(ctxb, wob, b_o, out);
}

// Round 12
// 163.899 us; speedup vs baseline: 1.1707x; 1.1707x over previous
//
#include <hip/hip_runtime.h>

#define BB 2
#define NN 2048
#define EE 768
#define HH 12
#define DD 64
#define MM (BB*NN)      // 4096
#define E3 (3*EE)       // 2304
// 1/sqrt(768) * log2(e): scores in log2 domain -> P = exp2(s)
#define QSCALE 0.05205877280961602f

typedef __bf16 bf16x8 __attribute__((ext_vector_type(8)));
typedef float  f32x4  __attribute__((ext_vector_type(4)));
typedef unsigned short u16x8 __attribute__((ext_vector_type(8)));

#define MFMA(a,b,c) __builtin_amdgcn_mfma_f32_16x16x32_bf16(a,b,c,0,0,0)

__device__ __forceinline__ unsigned short f2bf(float f) {
    unsigned int u = __float_as_uint(f);
    u += 0x7FFFu + ((u >> 16) & 1u);     // round-to-nearest-even
    return (unsigned short)(u >> 16);
}

typedef __attribute__((address_space(3))) unsigned int as3u32;
typedef __attribute__((address_space(1))) unsigned int as1u32;
__device__ __forceinline__ void gll16(const void* g, void* l) {
    // lane i deposits its 16B at lds_base + i*16 (wave-uniform dest base)
    __builtin_amdgcn_global_load_lds((const as1u32*)(uintptr_t)g,
                                     (as3u32*)(unsigned int)(uintptr_t)l, 16, 0, 0);
}

// ---------------------------------------------------------------------------
// fused f32 -> bf16 cast of x, w_qkv, w_o (contiguous dsts in ws)
// ---------------------------------------------------------------------------
#define XB4 786432   // (MM*EE)/4
#define WQ4 442368   // (E3*EE)/4
#define WO4 147456   // (EE*EE)/4
__global__ __launch_bounds__(256)
void cast3(const float* __restrict__ x, const float* __restrict__ wq,
           const float* __restrict__ wo, unsigned short* __restrict__ dst) {
    int i = blockIdx.x * 256 + threadIdx.x;
    const float* src;
    int off;
    if (i < XB4)            { src = x;  off = i; }
    else if (i < XB4+WQ4)   { src = wq; off = i - XB4; }
    else                    { src = wo; off = i - XB4 - WQ4; }
    float4 v = ((const float4*)src)[off];
    ushort4 o;
    o.x = f2bf(v.x); o.y = f2bf(v.y); o.z = f2bf(v.z); o.w = f2bf(v.w);
    ((ushort4*)dst)[i] = o;
}

// ---------------------------------------------------------------------------
// QKV GEMM: 128x64 tile, BK=32, 4 waves, wave tile 64x32 (4x2 frags).
// Grid (32,36) = 1152 blocks = 4.5 blocks/CU (was 576 = 2.25 -> latency-bound).
// Each block covers exactly one (h,t) 64-col section.
// Scatter: q (scaled) [B][H][N][D], k [B][H][N][D], v transposed [B][H][D][N].
// ---------------------------------------------------------------------------
__global__ __launch_bounds__(256)
void gemm_qkv(const unsigned short* __restrict__ A, const unsigned short* __restrict__ W,
              const float* __restrict__ bias,
              unsigned short* __restrict__ o0, unsigned short* __restrict__ o1,
              unsigned short* __restrict__ o2)
{
    __shared__ unsigned short As[128 * 32];   // 8 KB
    __shared__ unsigned short Bs[64 * 32];    // 4 KB

    const int tid = threadIdx.x;
    const int l = tid & 63;
    const int w = tid >> 6;
    const int m0 = blockIdx.x * 128;
    const int c0 = blockIdx.y * 64;
    const int wm = (w >> 1) * 64;
    const int wn = (w & 1) * 32;

    // staging: 12 chunks of 16 rows x 32 k (8 A + 4 B); wave stages 3w..3w+2
    const unsigned short* s_src[3];
    unsigned short* s_dst[3];
    #pragma unroll
    for (int s = 0; s < 3; ++s) {
        const int ch = 3*w + s;
        if (ch < 8) {
            s_src[s] = A + (size_t)(m0 + ch*16 + (l>>2)) * EE + (l&3)*8;
            s_dst[s] = &As[ch*512];
        } else {
            s_src[s] = W + (size_t)(c0 + (ch-8)*16 + (l>>2)) * EE + (l&3)*8;
            s_dst[s] = &Bs[(ch-8)*512];
        }
    }

    const f32x4 zero4 = {0.f, 0.f, 0.f, 0.f};
    f32x4 acc[4][2];
    #pragma unroll
    for (int i = 0; i < 4; ++i)
        #pragma unroll
        for (int j = 0; j < 2; ++j) acc[i][j] = zero4;

    for (int k0 = 0; k0 < EE; k0 += 32) {
        __syncthreads();
        #pragma unroll
        for (int s = 0; s < 3; ++s) gll16(s_src[s] + k0, s_dst[s]);
        __syncthreads();

        bf16x8 af[4], bf[2];
        #pragma unroll
        for (int i = 0; i < 4; ++i)
            af[i] = *(const bf16x8*)&As[(wm + 16*i + (l&15))*32 + (l>>4)*8];
        #pragma unroll
        for (int j = 0; j < 2; ++j)
            bf[j] = *(const bf16x8*)&Bs[(wn + 16*j + (l&15))*32 + (l>>4)*8];
        #pragma unroll
        for (int i = 0; i < 4; ++i)
            #pragma unroll
            for (int j = 0; j < 2; ++j)
                acc[i][j] = MFMA(af[i], bf[j], acc[i][j]);
    }

    // epilogue: C/D col = l&15, row = (l>>4)*4 + r. Block = one (h,t) section.
    const int sec = c0 >> 6;               // = hh*3 + tt
    const int hh = sec / 3;
    const int tt = sec - hh*3;
    #pragma unroll
    for (int j = 0; j < 2; ++j) {
        const int col = c0 + wn + 16*j + (l&15);
        const int dcol = wn + 16*j + (l&15);   // 0..63 within section
        const float bj = bias[col];
        #pragma unroll
        for (int i = 0; i < 4; ++i) {
            const int row0 = m0 + wm + 16*i + (l>>4)*4;
            const int b = row0 >> 11;
            const int n = row0 & (NN - 1);
            if (tt == 2) {
                ushort4 pk;
                pk.x = f2bf(acc[i][j][0] + bj);
                pk.y = f2bf(acc[i][j][1] + bj);
                pk.z = f2bf(acc[i][j][2] + bj);
                pk.w = f2bf(acc[i][j][3] + bj);
                *(ushort4*)&o2[(((size_t)b*HH + hh)*DD + dcol)*NN + n] = pk;
            } else {
                unsigned short* dst = (tt == 0) ? o0 : o1;
                #pragma unroll
                for (int r = 0; r < 4; ++r) {
                    float val = acc[i][j][r] + bj;
                    if (tt == 0) val *= QSCALE;
                    dst[(((size_t)b*HH + hh)*NN + n + r)*DD + dcol] = f2bf(val);
                }
            }
        }
    }
}

// ---------------------------------------------------------------------------
// Output GEMM: 64x64 tile, BK=32, 4 waves, wave tile 32x32 (2x2 frags).
// Grid (64,12) = 768 blocks = 3 blocks/CU (was 384 = 1.5 -> latency-bound).
// ---------------------------------------------------------------------------
__global__ __launch_bounds__(256)
void gemm_out(const unsigned short* __restrict__ A, const unsigned short* __restrict__ W,
              const float* __restrict__ bias, float* __restrict__ of)
{
    __shared__ unsigned short As[64 * 32];    // 4 KB
    __shared__ unsigned short Bs[64 * 32];    // 4 KB

    const int tid = threadIdx.x;
    const int l = tid & 63;
    const int w = tid >> 6;
    const int m0 = blockIdx.x * 64;
    const int c0 = blockIdx.y * 64;
    const int wm = (w >> 1) * 32;
    const int wn = (w & 1) * 32;

    // staging: 8 chunks of 16 rows x 32 k (4 A + 4 B); wave stages 2w, 2w+1
    const unsigned short* s_src[2];
    unsigned short* s_dst[2];
    #pragma unroll
    for (int s = 0; s < 2; ++s) {
        const int ch = 2*w + s;
        if (ch < 4) {
            s_src[s] = A + (size_t)(m0 + ch*16 + (l>>2)) * EE + (l&3)*8;
            s_dst[s] = &As[ch*512];
        } else {
            s_src[s] = W + (size_t)(c0 + (ch-4)*16 + (l>>2)) * EE + (l&3)*8;
            s_dst[s] = &Bs[(ch-4)*512];
        }
    }

    const f32x4 zero4 = {0.f, 0.f, 0.f, 0.f};
    f32x4 acc[2][2];
    #pragma unroll
    for (int i = 0; i < 2; ++i)
        #pragma unroll
        for (int j = 0; j < 2; ++j) acc[i][j] = zero4;

    for (int k0 = 0; k0 < EE; k0 += 32) {
        __syncthreads();
        #pragma unroll
        for (int s = 0; s < 2; ++s) gll16(s_src[s] + k0, s_dst[s]);
        __syncthreads();

        bf16x8 af[2], bf[2];
        #pragma unroll
        for (int i = 0; i < 2; ++i)
            af[i] = *(const bf16x8*)&As[(wm + 16*i + (l&15))*32 + (l>>4)*8];
        #pragma unroll
        for (int j = 0; j < 2; ++j)
            bf[j] = *(const bf16x8*)&Bs[(wn + 16*j + (l&15))*32 + (l>>4)*8];
        #pragma unroll
        for (int i = 0; i < 2; ++i)
            #pragma unroll
            for (int j = 0; j < 2; ++j)
                acc[i][j] = MFMA(af[i], bf[j], acc[i][j]);
    }

    #pragma unroll
    for (int j = 0; j < 2; ++j) {
        const int col = c0 + wn + 16*j + (l&15);
        const float bj = bias[col];
        #pragma unroll
        for (int i = 0; i < 2; ++i) {
            #pragma unroll
            for (int r = 0; r < 4; ++r) {
                const int row = m0 + wm + 16*i + (l>>4)*4 + r;
                of[(size_t)row * EE + col] = acc[i][j][r] + bj;
            }
        }
    }
}

// ---------------------------------------------------------------------------
// MFMA flash attention (r10 verbatim, best measured 53.1 us): r7 structure
// with 128-KEY TILES (two 64-key halves per barrier pair).
// Block = 64 Q of one (b,h), 4 waves x 16 q. Grid 768: bh = id%24 (XCD-grouped).
// S^T = K*Q^T, per-lane no-max softmax, deferred denominator.
// Ks/Vt: per half [row][64], 16B-chunk ^ (row&7); Pq per-wave per-half,
// 8B-chunk ^ (q&14). LDS 48 KB -> 3 blocks/CU.
// ---------------------------------------------------------------------------
__global__ __launch_bounds__(256)
void attn_mfma(const unsigned short* __restrict__ Q, const unsigned short* __restrict__ K,
               const unsigned short* __restrict__ Vt_g, unsigned short* __restrict__ ctx)
{
    __shared__ unsigned short Ks[2 * 64 * 64];       // 16 KB (two halves)
    __shared__ unsigned short Vt[2 * 64 * 64];       // 16 KB
    __shared__ unsigned short Pq[4 * 2 * 16 * 64];   // 16 KB, [wave][half][q][64]

    const int tid = threadIdx.x;
    const int l = tid & 63;
    const int w = tid >> 6;
    const int quad = l >> 4;
    const int lc = l & 15;
    const int x7 = lc & 7;

    const int id = blockIdx.x;
    const int bh = id % 24;              // b*HH + h
    const int bq = id / 24;              // q-tile
    const int b  = bh / 12;
    const int h  = bh - b*12;
    const size_t hb = (size_t)bh * NN * DD;

    const f32x4 zero4 = {0.f, 0.f, 0.f, 0.f};

    // Q B-frags (pre-scaled by QSCALE): B[n=q=lc][k=d=quad*8+j]
    const int qrow = bq*64 + w*16 + lc;
    const bf16x8 qf0 = *(const bf16x8*)(Q + hb + (size_t)qrow*DD +      quad*8);
    const bf16x8 qf1 = *(const bf16x8*)(Q + hb + (size_t)qrow*DD + 32 + quad*8);

    f32x4 o[4];
    #pragma unroll
    for (int dj = 0; dj < 4; ++dj) o[dj] = zero4;
    float lsum = 0.f;

    // staging: 256 threads, row = tid>>2 (64 rows/half), sc = tid&3 (2 chunks)
    const int srow = tid >> 2;
    const int sc = tid & 3;
    const unsigned short* kbase = K + hb + (size_t)srow*DD + sc*16;
    const unsigned short* vbase = Vt_g + hb + (size_t)srow*NN + sc*16;
    const int c0s = ((2*sc)     ^ (srow & 7)) * 8;
    const int c1s = ((2*sc + 1) ^ (srow & 7)) * 8;
    const int so = srow * 64;

    // frag-read swizzled chunk offsets (same for both halves)
    const int chq0 = ((    quad) ^ x7) * 8;
    const int chq1 = ((4 + quad) ^ x7) * 8;
    const int pw = w * 2048;
    const int prd0 = lc*64 + (((    2*quad) ^ (lc & 14)) * 4);
    const int prd1 = lc*64 + (((8 + 2*quad) ^ (lc & 14)) * 4);

    for (int kt = 0; kt < NN/128; ++kt) {
        // global loads for both 64-key halves
        const unsigned short* k0p = kbase + (size_t)kt*128*DD;
        const unsigned short* k1p = k0p + (size_t)64*DD;
        const unsigned short* v0p = vbase + kt*128;
        const unsigned short* v1p = v0p + 64;
        u16x8 ka0 = *(const u16x8*)k0p;
        u16x8 ka1 = *(const u16x8*)(k0p + 8);
        u16x8 kb0 = *(const u16x8*)k1p;
        u16x8 kb1 = *(const u16x8*)(k1p + 8);
        u16x8 va0 = *(const u16x8*)v0p;
        u16x8 va1 = *(const u16x8*)(v0p + 8);
        u16x8 vb0 = *(const u16x8*)v1p;
        u16x8 vb1 = *(const u16x8*)(v1p + 8);
        __syncthreads();                 // prior-iter readers done
        *(u16x8*)&Ks[so + c0s] = ka0;
        *(u16x8*)&Ks[so + c1s] = ka1;
        *(u16x8*)&Ks[4096 + so + c0s] = kb0;
        *(u16x8*)&Ks[4096 + so + c1s] = kb1;
        *(u16x8*)&Vt[so + c0s] = va0;
        *(u16x8*)&Vt[so + c1s] = va1;
        *(u16x8*)&Vt[4096 + so + c0s] = vb0;
        *(u16x8*)&Vt[4096 + so + c1s] = vb1;
        __syncthreads();                 // writers done

        #pragma unroll
        for (int hf = 0; hf < 2; ++hf) {
            const int base = hf * 4096;
            const int pb = pw + hf * 1024;

            // S^T = K Q^T : 4 key-frags x 2 k-steps
            f32x4 st[4];
            #pragma unroll
            for (int jf = 0; jf < 4; ++jf) {
                bf16x8 kf0 = *(const bf16x8*)&Ks[base + (16*jf + lc)*64 + chq0];
                bf16x8 kf1 = *(const bf16x8*)&Ks[base + (16*jf + lc)*64 + chq1];
                f32x4 acc0 = MFMA(kf0, qf0, zero4);
                st[jf] = MFMA(kf1, qf1, acc0);
            }

            // P = exp2(S^T). Lane holds keys 16*jf + quad*4 + r, q = lc.
            #pragma unroll
            for (int jf = 0; jf < 4; ++jf) {
                float e0 = __builtin_amdgcn_exp2f(st[jf][0]);
                float e1 = __builtin_amdgcn_exp2f(st[jf][1]);
                float e2 = __builtin_amdgcn_exp2f(st[jf][2]);
                float e3 = __builtin_amdgcn_exp2f(st[jf][3]);
                lsum += (e0 + e1) + (e2 + e3);
                ushort4 pk;
                pk.x = f2bf(e0); pk.y = f2bf(e1); pk.z = f2bf(e2); pk.w = f2bf(e3);
                *(ushort4*)&Pq[pb + lc*64 + (((4*jf + quad) ^ (lc & 14)) * 4)] = pk;
            }

            // O^T += V^T P^T
            bf16x8 pf0 = *(const bf16x8*)&Pq[pb + prd0];
            bf16x8 pf1 = *(const bf16x8*)&Pq[pb + prd1];
            #pragma unroll
            for (int dj = 0; dj < 4; ++dj) {
                bf16x8 vf0 = *(const bf16x8*)&Vt[base + (16*dj + lc)*64 + chq0];
                bf16x8 vf1 = *(const bf16x8*)&Vt[base + (16*dj + lc)*64 + chq1];
                o[dj] = MFMA(vf0, pf0, o[dj]);
                o[dj] = MFMA(vf1, pf1, o[dj]);
            }
        }
    }

    // final denominator: reduce across the 4 quads (same q = lc)
    lsum += __shfl_xor(lsum, 16);
    lsum += __shfl_xor(lsum, 32);
    const float inv = 1.f / lsum;

    // O^T C-layout: row = d = 16*dj + quad*4 + r, col = q = lc -> packed store
    const int n = bq*64 + w*16 + lc;
    #pragma unroll
    for (int dj = 0; dj < 4; ++dj) {
        ushort4 pk;
        pk.x = f2bf(o[dj][0] * inv);
        pk.y = f2bf(o[dj][1] * inv);
        pk.z = f2bf(o[dj][2] * inv);
        pk.w = f2bf(o[dj][3] * inv);
        *(ushort4*)&ctx[((size_t)(b*NN + n))*EE + h*DD + 16*dj + quad*4] = pk;
    }
}

// ---------------------------------------------------------------------------
extern "C" void kernel_launch(void* const* d_in, const int* in_sizes, int n_in,
                              void* d_out, int out_size, void* d_ws, size_t ws_size,
                              hipStream_t stream)
{
    const float* x     = (const float*)d_in[0];
    const float* w_qkv = (const float*)d_in[1];
    const float* b_qkv = (const float*)d_in[2];
    const float* w_o   = (const float*)d_in[3];
    const float* b_o   = (const float*)d_in[4];
    float* out = (float*)d_out;

    unsigned short* wsu = (unsigned short*)d_ws;
    const size_t XB = (size_t)MM * EE;
    const size_t WQ = (size_t)E3 * EE;
    const size_t WO = (size_t)EE * EE;
    const size_t HS = (size_t)BB * HH * NN * DD;
    unsigned short* xb   = wsu;
    unsigned short* wqb  = xb  + XB;
    unsigned short* wob  = wqb + WQ;
    unsigned short* qb   = wob + WO;      // [B][H][N][D] (scaled)
    unsigned short* kb   = qb  + HS;      // [B][H][N][D]
    unsigned short* vtb  = kb  + HS;      // [B][H][D][N]
    unsigned short* ctxb = vtb + HS;

    cast3<<<(XB4 + WQ4 + WO4)/256, 256, 0, stream>>>(x, w_qkv, w_o, xb);

    dim3 g1(MM/128, E3/64);    // 32 x 36 = 1152 blocks
    gemm_qkv<<<g1, 256, 0, stream>>>(xb, wqb, b_qkv, qb, kb, vtb);

    attn_mfma<<<768, 256, 0, stream>>>(qb, kb, vtb, ctxb);

    dim3 g3(MM/64, EE/64);     // 64 x 12 = 768 blocks
    gemm_out<<<g3, 256, 0, stream>>>(ctxb, wob, b_o, out);
}